// Round 6
// baseline (4135.266 us; speedup 1.0000x reference)
//
#include <hip/hip_runtime.h>
#include <hip/hip_bf16.h>

// ---------------------------------------------------------------------------
// 2-layer tanh RNN + FC head on MI355X (gfx950).
// Round 9: r8 (LDS-resident weights, validated XCD-local protocol) with the
// L1 input-projection SOFTWARE-PIPELINED off the serial chain:
//   ip_{t+1} is computed AFTER signaling h1_t (hides under peers' signal RT;
//   h0_{t+1} exists because L0 free-runs ahead), so the h1 chain is only
//   wait -> recurrence -> reduce -> store -> signal.
// Plus: wait16 skips the agent-acquire fence in LOCAL mode. The fence
// invalidates L1+L2 (agent coherence point = LLC) and was flushing the XCD
// L2 every step, defeating Wih1/pre0 L2 residency. Local-mode ordering is
// fence-free-safe: producer h-stores are vmcnt-drained to L2 BEFORE its
// agent flag store; consumer sees flag => h in L2; h addresses are
// read-once per WG (no stale-L1 channel) -- the exact mechanism already
// validated by r6/r8's passing h-path. Fallback mode keeps the fence.
//   B=64 S=512 I=256 H=1024 O=256
//   grid 256: bx%8 even -> group (bx%8)/2, rank bx/8 (0..31):
//     rank<16 : layer-0 WG, 64 cols;  rank>=16: layer-1 WG, 64 cols
//   bx%8 odd -> exit. 151KB LDS -> 1 WG/CU.
// ---------------------------------------------------------------------------

typedef __attribute__((ext_vector_type(4))) float f32x4;
typedef __attribute__((ext_vector_type(8))) short bf16x8;
typedef __attribute__((ext_vector_type(4))) int   i32x4;
typedef __attribute__((ext_vector_type(4))) short s16x4;

#define B_  64
#define S_  512
#define I_  256
#define H_  1024
#define O_  256
#define M_  (B_ * S_)     // 32768
#define SH_ (S_ * H_)     // 524288 (row stride of h-seq / pre in elements)
#define NACT 128          // active WGs (4 groups x 32)
#define POISON_TAG 0xFFu  // nonzero, != any real tag (tags are 1..16)

static __device__ __forceinline__ unsigned short f2bf(float f) {
  union { float f; unsigned u; } v; v.f = f;
  unsigned r = v.u + 0x7fffu + ((v.u >> 16) & 1u);   // RNE
  return (unsigned short)(r >> 16);
}
static __device__ __forceinline__ float bf2f(unsigned short b) {
  union { unsigned u; float f; } v; v.u = ((unsigned)b) << 16;
  return v.f;
}
static __device__ __forceinline__ float tanh_fast(float x) {
  float e = __expf(2.f * x);
  return 1.f - 2.f / (e + 1.f);
}
static __device__ __forceinline__ bf16x8 as_bf16x8(i32x4 v) {
  union { i32x4 i; bf16x8 b; } u; u.i = v; return u.b;
}

// ---- sync primitives (flags ALWAYS agent scope — validated r2/r4/r6/r8) ---

// wait until all 16 producer counters >= v.
// local==true: skip the acquire fence (see header comment) to keep L2 warm.
static __device__ __forceinline__ void wait16(const unsigned* sig, int v,
                                              bool local) {
  for (;;) {
    unsigned mn = 0xffffffffu;
#pragma unroll
    for (int i = 0; i < 16; ++i) {
      unsigned x = __hip_atomic_load(&sig[i], __ATOMIC_RELAXED,
                                     __HIP_MEMORY_SCOPE_AGENT);
      mn = x < mn ? x : mn;
    }
    if (mn >= (unsigned)v) break;
    __builtin_amdgcn_s_sleep(2);
  }
  if (!local) __builtin_amdgcn_fence(__ATOMIC_ACQUIRE, "agent");
}

static __device__ __forceinline__ void sig_store(unsigned* p, int v) {
  // prior h-stores drained by the preceding barrier's vmcnt(0)
  __hip_atomic_store(p, (unsigned)v, __ATOMIC_RELAXED,
                     __HIP_MEMORY_SCOPE_AGENT);
}

// h-state store: plain (write-through to own-XCD L2) when the group is
// verified co-located; agent-scope (LLC) otherwise.
static __device__ __forceinline__ void h_store(unsigned short* p,
                                               unsigned short v, bool local) {
  if (local) *p = v;
  else __hip_atomic_store(p, v, __ATOMIC_RELAXED, __HIP_MEMORY_SCOPE_AGENT);
}

// ---------------- f32 -> bf16 conversion (vectorized) ----------------------
__global__ void cvt_bf16(const float* __restrict__ src,
                         unsigned short* __restrict__ dst, int n4) {
  int i = blockIdx.x * blockDim.x + threadIdx.x;
  if (i < n4) {
    f32x4 v = ((const f32x4*)src)[i];
    s16x4 o;
    o[0] = (short)f2bf(v[0]); o[1] = (short)f2bf(v[1]);
    o[2] = (short)f2bf(v[2]); o[3] = (short)f2bf(v[3]);
    ((s16x4*)dst)[i] = o;
  }
}

// ---------------- big MFMA GEMM: C[M,N] = A[M,K]@W[N,K]^T + b1 (+b2) -------
template <bool BF16OUT>
__global__ __launch_bounds__(256)
void gemm_bf16(const unsigned short* __restrict__ A,
               const unsigned short* __restrict__ W,
               const float* __restrict__ b1, const float* __restrict__ b2,
               void* __restrict__ Cv, int Mx, int Nx, int Kx) {
  __shared__ __align__(16) unsigned short As[128 * 40];
  __shared__ __align__(16) unsigned short Bs[128 * 40];
  const int tid  = threadIdx.x;
  const int m0   = blockIdx.y * 128;
  const int n0   = blockIdx.x * 128;
  const int w    = tid >> 6, lane = tid & 63;
  const int quad = lane >> 4, l15 = lane & 15;
  const int wm = (w & 1) * 64, wn = (w >> 1) * 64;

  f32x4 acc[4][4] = {};

  for (int k0 = 0; k0 < Kx; k0 += 32) {
#pragma unroll
    for (int i = 0; i < 2; ++i) {
      int c = tid + i * 256;
      int row = c >> 2, kc = c & 3;
      *(i32x4*)&As[row * 40 + kc * 8] =
          *(const i32x4*)&A[(size_t)(m0 + row) * Kx + k0 + kc * 8];
      *(i32x4*)&Bs[row * 40 + kc * 8] =
          *(const i32x4*)&W[(size_t)(n0 + row) * Kx + k0 + kc * 8];
    }
    __syncthreads();
    bf16x8 af[4], bg[4];
#pragma unroll
    for (int im = 0; im < 4; ++im)
      af[im] = *(const bf16x8*)&As[(wm + im * 16 + l15) * 40 + quad * 8];
#pragma unroll
    for (int in = 0; in < 4; ++in)
      bg[in] = *(const bf16x8*)&Bs[(wn + in * 16 + l15) * 40 + quad * 8];
#pragma unroll
    for (int im = 0; im < 4; ++im)
#pragma unroll
      for (int in = 0; in < 4; ++in)
        acc[im][in] = __builtin_amdgcn_mfma_f32_16x16x32_bf16(
            af[im], bg[in], acc[im][in], 0, 0, 0);
    __syncthreads();
  }

#pragma unroll
  for (int in = 0; in < 4; ++in) {
    int n = n0 + wn + in * 16 + l15;
    float bv = b1 ? b1[n] : 0.f;
    if (b2) bv += b2[n];
#pragma unroll
    for (int im = 0; im < 4; ++im) {
      int mb = m0 + wm + im * 16 + quad * 4;   // C/D: row = quad*4+reg, col = l15
#pragma unroll
      for (int r = 0; r < 4; ++r) {
        float val = acc[im][in][r] + bv;
        size_t o = (size_t)(mb + r) * Nx + n;
        if (BF16OUT) ((unsigned short*)Cv)[o] = f2bf(val);
        else         ((float*)Cv)[o] = val;
      }
    }
  }
}

// ---------------- fused dual-layer persistent recurrence -------------------
// flags layout (u32):
//   [0..127]             xcdtab: published (XCC_ID+1) per active WG
//   128 + (g*3+k)*64     sig lines, 16 used + 48 pad (no 128B-line sharing):
//                        k=0 sigA (L0->L0), k=1 sigB (L0->L1), k=2 sigC
//                        (L1->L1). Producer p stores t+1 after step t.
__global__ __launch_bounds__(256, 1)
void rnn_fused(const unsigned short* __restrict__ Whh0,   // [H,H] bf16
               const unsigned short* __restrict__ Wih1,   // [H,H] bf16
               const unsigned short* __restrict__ Whh1,   // [H,H] bf16
               const unsigned short* __restrict__ pre0,   // [B,S,H] bf16
               const float* __restrict__ b_ih_1,
               const float* __restrict__ b_hh_1,
               unsigned short* __restrict__ h0seq,        // [B,S,H] bf16
               unsigned short* __restrict__ h1seq,        // [B,S,H] bf16
               unsigned int* __restrict__ flags)          // zeroed, 1024 u32
{
  const int bx  = blockIdx.x;
  const int res = bx & 7;
  if (res & 1) return;              // idle half of the grid
  const int g   = res >> 1;         // group 0..3 (16 batches each)
  const int r   = bx >> 3;          // rank within XCD slot, 0..31
  const int tid = threadIdx.x;
  const int w    = tid >> 6;        // wave = k-slice (256 wide)
  const int lane = tid & 63;
  const int quad = lane >> 4, l15 = lane & 15;
  const int n0   = (r & 15) * 64;   // 64 output cols per WG (both layers)

  unsigned* xcdtab = flags;
  unsigned* sigA = flags + 128 + (g * 3 + 0) * 64;
  unsigned* sigB = flags + 128 + (g * 3 + 1) * 64;
  unsigned* sigC = flags + 128 + (g * 3 + 2) * 64;

  // 128KB fragment-ordered weight store + 20KB reduce buffer = 151.5KB LDS.
  __shared__ __align__(16) unsigned short Wlds[65536];
  __shared__ __align__(16) float q[4][4][16][20];  // [wave][ntile][col][4r pad20]
  __shared__ int s_local;

  // ---- setup: discover XCD, publish, verify co-location (BOUNDED, r6) ----
  if (tid == 0) {
    // HW_REG_XCC_ID = id 20, offset 0, size 4  (simm16 = (size-1)<<11 | id)
    unsigned tag =
        ((unsigned)__builtin_amdgcn_s_getreg((3 << 11) | 20) & 0xFu) + 1u;
    __hip_atomic_store(&xcdtab[g * 32 + r], tag, __ATOMIC_RELEASE,
                       __HIP_MEMORY_SCOPE_AGENT);
    unsigned long long t0 = __builtin_amdgcn_s_memrealtime();
    bool timeout = false;
    for (;;) {
      bool all = true;
      for (int i = 0; i < NACT; ++i)
        if (__hip_atomic_load(&xcdtab[i], __ATOMIC_RELAXED,
                              __HIP_MEMORY_SCOPE_AGENT) == 0u) {
          all = false; break;
        }
      if (all) break;
      if (__builtin_amdgcn_s_memrealtime() - t0 > 5000000ull) {
        timeout = true; break;
      }
      __builtin_amdgcn_s_sleep(8);
    }
    int verdict = 0;
    if (timeout) {
      __hip_atomic_store(&xcdtab[g * 32 + r], POISON_TAG, __ATOMIC_RELAXED,
                         __HIP_MEMORY_SCOPE_AGENT);
    } else {
      __builtin_amdgcn_fence(__ATOMIC_ACQUIRE, "agent");
      bool loc = true;
      int  cnt = 0;
      for (int i = 0; i < NACT; ++i) {
        unsigned v = __hip_atomic_load(&xcdtab[i], __ATOMIC_RELAXED,
                                       __HIP_MEMORY_SCOPE_AGENT);
        if ((i >> 5) == g) loc &= (v == tag);
        cnt += (v == tag) ? 1 : 0;
      }
      verdict = (loc && cnt == 32) ? 1 : 0;
    }
    s_local = verdict;
  }

  // per-lane LDS fragment base (w's 32 frags start at frag w*32)
  unsigned short* Wl = &Wlds[(w * 32 * 64 + lane) * 8];

  if (r < 16) {
    // ================= layer 0: 16 WGs/group, 64 cols =================
    {
      const unsigned short* wp =
          Whh0 + (size_t)(n0 + l15) * H_ + w * 256 + quad * 8;
#pragma unroll
      for (int i = 0; i < 4; ++i)
#pragma unroll
        for (int kk = 0; kk < 8; ++kk)
          *(i32x4*)&Wl[(i * 8 + kk) * 512] =
              *(const i32x4*)(wp + (size_t)i * 16 * H_ + kk * 32);
    }
    __syncthreads();                       // Wlds ready; s_local visible
    const bool local = (s_local != 0);

    for (int t = 0; t < S_; ++t) {
      float pv[4];   // pre0 prefetch: issue before the wait
      {
        const unsigned short* pp = pre0 + (size_t)(g * 16 + quad * 4) * SH_ +
                                   (size_t)t * H_ + n0 + w * 16 + l15;
#pragma unroll
        for (int u = 0; u < 4; ++u) pv[u] = bf2f(pp[(size_t)u * SH_]);
      }

      f32x4 acc[4] = {};
      if (t > 0) {
        if (tid == 0) wait16(sigA, t, local);
        __syncthreads();
        const unsigned short* hp = h0seq + (size_t)(g * 16 + l15) * SH_ +
                                   (size_t)(t - 1) * H_ + w * 256 + quad * 8;
        bf16x8 Af[8];
#pragma unroll
        for (int kk = 0; kk < 8; ++kk) Af[kk] = *(const bf16x8*)(hp + kk * 32);
#pragma unroll
        for (int kk = 0; kk < 8; ++kk)
#pragma unroll
          for (int i = 0; i < 4; ++i)
            acc[i] = __builtin_amdgcn_mfma_f32_16x16x32_bf16(
                Af[kk], *(const bf16x8*)&Wl[(i * 8 + kk) * 512],
                acc[i], 0, 0, 0);
      }

      // split-K reduce through LDS
#pragma unroll
      for (int i = 0; i < 4; ++i) *(f32x4*)&q[w][i][l15][quad * 4] = acc[i];
      __syncthreads();
      f32x4 s = {};
#pragma unroll
      for (int wp2 = 0; wp2 < 4; ++wp2) {
        f32x4 v = *(const f32x4*)&q[wp2][w][l15][quad * 4];
#pragma unroll
        for (int u = 0; u < 4; ++u) s[u] += v[u];
      }

#pragma unroll
      for (int u = 0; u < 4; ++u) {
        unsigned short hb = f2bf(tanh_fast(pv[u] + s[u]));
        size_t o = (size_t)(g * 16 + quad * 4 + u) * SH_ + (size_t)t * H_ +
                   n0 + w * 16 + l15;
        h_store(&h0seq[o], hb, local);
      }
      __syncthreads();   // vmcnt(0) drain of all waves' h stores; WAR on q
      if (tid == 0) {
        sig_store(&sigA[r], t + 1);
        sig_store(&sigB[r], t + 1);
      }
    }
  } else {
    // ================= layer 1: 16 WGs/group, 64 cols =================
    const int p1 = r - 16;
    // stage Whh1 (recurrent, chain-critical) into LDS; Wih1 streams from L2
    {
      const unsigned short* wp =
          Whh1 + (size_t)(n0 + l15) * H_ + w * 256 + quad * 8;
#pragma unroll
      for (int i = 0; i < 4; ++i)
#pragma unroll
        for (int kk = 0; kk < 8; ++kk)
          *(i32x4*)&Wl[(i * 8 + kk) * 512] =
              *(const i32x4*)(wp + (size_t)i * 16 * H_ + kk * 32);
    }
    __syncthreads();
    const bool local = (s_local != 0);

    const unsigned short* wpi =
        Wih1 + (size_t)(n0 + l15) * H_ + w * 256 + quad * 8;

    float bias;
    {
      int n = n0 + w * 16 + l15;
      bias = b_ih_1[n] + b_hh_1[n];
    }

    // input projection for step tt -> ipacc (OFF the h1 serial chain)
    f32x4 ipacc[4];
    auto ip_comp = [&](int tt) {
      const unsigned short* hp = h0seq + (size_t)(g * 16 + l15) * SH_ +
                                 (size_t)tt * H_ + w * 256 + quad * 8;
      bf16x8 Af[8];
#pragma unroll
      for (int kk = 0; kk < 8; ++kk) Af[kk] = *(const bf16x8*)(hp + kk * 32);
#pragma unroll
      for (int i = 0; i < 4; ++i) ipacc[i] = (f32x4){};
      i32x4 wa[8], wb[8];
#pragma unroll
      for (int kk = 0; kk < 8; ++kk)
        wa[kk] = *(const i32x4*)(wpi + (size_t)0 * 16 * H_ + kk * 32);
#pragma unroll
      for (int kk = 0; kk < 8; ++kk)
        wb[kk] = *(const i32x4*)(wpi + (size_t)1 * 16 * H_ + kk * 32);
#pragma unroll
      for (int kk = 0; kk < 8; ++kk)
        ipacc[0] = __builtin_amdgcn_mfma_f32_16x16x32_bf16(
            Af[kk], as_bf16x8(wa[kk]), ipacc[0], 0, 0, 0);
#pragma unroll
      for (int kk = 0; kk < 8; ++kk)
        wa[kk] = *(const i32x4*)(wpi + (size_t)2 * 16 * H_ + kk * 32);
#pragma unroll
      for (int kk = 0; kk < 8; ++kk)
        ipacc[1] = __builtin_amdgcn_mfma_f32_16x16x32_bf16(
            Af[kk], as_bf16x8(wb[kk]), ipacc[1], 0, 0, 0);
#pragma unroll
      for (int kk = 0; kk < 8; ++kk)
        wb[kk] = *(const i32x4*)(wpi + (size_t)3 * 16 * H_ + kk * 32);
#pragma unroll
      for (int kk = 0; kk < 8; ++kk)
        ipacc[2] = __builtin_amdgcn_mfma_f32_16x16x32_bf16(
            Af[kk], as_bf16x8(wa[kk]), ipacc[2], 0, 0, 0);
#pragma unroll
      for (int kk = 0; kk < 8; ++kk)
        ipacc[3] = __builtin_amdgcn_mfma_f32_16x16x32_bf16(
            Af[kk], as_bf16x8(wb[kk]), ipacc[3], 0, 0, 0);
    };

    // prologue: ip for t=0 (needs h0_0 => sigB >= 1)
    if (tid == 0) wait16(sigB, 1, local);
    __syncthreads();
    ip_comp(0);

    for (int t = 0; t < S_; ++t) {
      f32x4 acc[4];
#pragma unroll
      for (int i = 0; i < 4; ++i) acc[i] = ipacc[i];

      // --- recurrence: the serial chain (needs h1_{t-1}); Wr from LDS
      if (t > 0) {
        if (tid == 0) wait16(sigC, t, local);
        __syncthreads();
        const unsigned short* hp = h1seq + (size_t)(g * 16 + l15) * SH_ +
                                   (size_t)(t - 1) * H_ + w * 256 + quad * 8;
        bf16x8 Af[8];
#pragma unroll
        for (int kk = 0; kk < 8; ++kk) Af[kk] = *(const bf16x8*)(hp + kk * 32);
#pragma unroll
        for (int kk = 0; kk < 8; ++kk)
#pragma unroll
          for (int i = 0; i < 4; ++i)
            acc[i] = __builtin_amdgcn_mfma_f32_16x16x32_bf16(
                Af[kk], *(const bf16x8*)&Wl[(i * 8 + kk) * 512],
                acc[i], 0, 0, 0);
      }

      // --- split-K reduce + epilogue (all 4 waves; wave w owns ntile w)
#pragma unroll
      for (int i = 0; i < 4; ++i) *(f32x4*)&q[w][i][l15][quad * 4] = acc[i];
      __syncthreads();
      f32x4 s = {};
#pragma unroll
      for (int wp2 = 0; wp2 < 4; ++wp2) {
        f32x4 v = *(const f32x4*)&q[wp2][w][l15][quad * 4];
#pragma unroll
        for (int u = 0; u < 4; ++u) s[u] += v[u];
      }
#pragma unroll
      for (int u = 0; u < 4; ++u) {
        unsigned short hb = f2bf(tanh_fast(bias + s[u]));
        size_t o = (size_t)(g * 16 + quad * 4 + u) * SH_ + (size_t)t * H_ +
                   n0 + w * 16 + l15;
        h_store(&h1seq[o], hb, local);
      }
      __syncthreads();   // drain before the flag publish
      if (tid == 0) sig_store(&sigC[p1], t + 1);

      // --- pipelined ip for t+1 (hides under peers' signal round-trip)
      if (t < S_ - 1) {
        if (tid == 0) wait16(sigB, t + 2, local);
        __syncthreads();
        ip_comp(t + 1);
      }
    }
  }
}

// ---------------------------------------------------------------------------
extern "C" void kernel_launch(void* const* d_in, const int* in_sizes, int n_in,
                              void* d_out, int out_size, void* d_ws, size_t ws_size,
                              hipStream_t stream) {
  const float* x      = (const float*)d_in[0];
  const float* W_ih_0 = (const float*)d_in[1];
  const float* W_hh_0 = (const float*)d_in[2];
  const float* b_ih_0 = (const float*)d_in[3];
  const float* b_hh_0 = (const float*)d_in[4];
  const float* W_ih_1 = (const float*)d_in[5];
  const float* W_hh_1 = (const float*)d_in[6];
  const float* b_ih_1 = (const float*)d_in[7];
  const float* b_hh_1 = (const float*)d_in[8];
  const float* fc_w   = (const float*)d_in[9];
  const float* fc_b   = (const float*)d_in[10];
  float* out = (float*)d_out;

  char* ws = (char*)d_ws;
  size_t off = 0;
  auto alloc = [&](size_t bytes) { char* p = ws + off; off += (bytes + 255) & ~(size_t)255; return p; };
  unsigned short* xb    = (unsigned short*)alloc((size_t)M_ * I_ * 2);   // 16.8 MB
  unsigned short* wih0b = (unsigned short*)alloc((size_t)H_ * I_ * 2);
  unsigned short* whh0b = (unsigned short*)alloc((size_t)H_ * H_ * 2);
  unsigned short* wih1b = (unsigned short*)alloc((size_t)H_ * H_ * 2);
  unsigned short* whh1b = (unsigned short*)alloc((size_t)H_ * H_ * 2);
  unsigned short* fcwb  = (unsigned short*)alloc((size_t)O_ * H_ * 2);
  unsigned int*   flags = (unsigned int*)alloc(1024 * 4);                // 4 KB
  unsigned short* pre0b = (unsigned short*)alloc((size_t)M_ * H_ * 2);   // 67 MB
  unsigned short* h0seq = (unsigned short*)alloc((size_t)M_ * H_ * 2);   // 67 MB
  unsigned short* h1seq = (unsigned short*)alloc((size_t)M_ * H_ * 2);   // 67 MB

  hipMemsetAsync(flags, 0, 1024 * 4, stream);

  auto cvt = [&](const float* s, unsigned short* d, int n) {
    int n4 = n / 4;
    cvt_bf16<<<(n4 + 255) / 256, 256, 0, stream>>>(s, d, n4);
  };
  cvt(x,      xb,    M_ * I_);
  cvt(W_ih_0, wih0b, H_ * I_);
  cvt(W_hh_0, whh0b, H_ * H_);
  cvt(W_ih_1, wih1b, H_ * H_);
  cvt(W_hh_1, whh1b, H_ * H_);
  cvt(fc_w,   fcwb,  O_ * H_);

  // pre0 = x @ W_ih0^T + b_ih0 + b_hh0  (bf16 out)
  gemm_bf16<true><<<dim3(H_ / 128, M_ / 128), 256, 0, stream>>>(
      xb, wih0b, b_ih_0, b_hh_0, pre0b, M_, H_, I_);

  // fused dual-layer recurrence (LDS weights, pipelined L1 input projection)
  rnn_fused<<<256, 256, 0, stream>>>(whh0b, wih1b, whh1b, pre0b,
                                     b_ih_1, b_hh_1, h0seq, h1seq, flags);

  // FC head
  gemm_bf16<false><<<dim3(O_ / 128, M_ / 128), 256, 0, stream>>>(
      h1seq, fcwb, fc_b, nullptr, out, M_, O_, H_);
}